// Round 9
// baseline (1556.982 us; speedup 1.0000x reference)
//
#include <hip/hip_runtime.h>
#include <stdint.h>
#include <stddef.h>

// ---------------------------------------------------------------------------
// TwoHemiRNNTanh_asymmetric_single_readout  (B=512, T=400, hidden 258)
// R9: (1) W truly register-resident via asm pin (R8 counters showed VGPR=64
// -> compiler was re-loading W from L1 every step); (2) 4-way k-split ->
// allreduce is 2 DPP adds, no ds_swizzle latency; (3) gen_uv/gen_c fused
// into the scan (u,v in LDS prologue; C generated per-chunk in flush phase).
// ---------------------------------------------------------------------------

typedef uint32_t u32x4 __attribute__((ext_vector_type(4)));
typedef __fp16   f16x2 __attribute__((ext_vector_type(2)));

#define TF_ROUND(x0, x1, r) { x0 += x1; x1 = ((x1) << (r)) | ((x1) >> (32 - (r))); x1 ^= x0; }

__host__ __device__ inline void tf2x32(uint32_t k0, uint32_t k1, uint32_t x0, uint32_t x1,
                                       uint32_t& o0, uint32_t& o1) {
  uint32_t ks2 = k0 ^ k1 ^ 0x1BD11BDAu;
  x0 += k0; x1 += k1;
  TF_ROUND(x0, x1, 13) TF_ROUND(x0, x1, 15) TF_ROUND(x0, x1, 26) TF_ROUND(x0, x1, 6)
  x0 += k1; x1 += ks2 + 1u;
  TF_ROUND(x0, x1, 17) TF_ROUND(x0, x1, 29) TF_ROUND(x0, x1, 16) TF_ROUND(x0, x1, 24)
  x0 += ks2; x1 += k0 + 2u;
  TF_ROUND(x0, x1, 13) TF_ROUND(x0, x1, 15) TF_ROUND(x0, x1, 26) TF_ROUND(x0, x1, 6)
  x0 += k0; x1 += k1 + 3u;
  TF_ROUND(x0, x1, 17) TF_ROUND(x0, x1, 29) TF_ROUND(x0, x1, 16) TF_ROUND(x0, x1, 24)
  x0 += k1; x1 += ks2 + 4u;
  TF_ROUND(x0, x1, 13) TF_ROUND(x0, x1, 15) TF_ROUND(x0, x1, 26) TF_ROUND(x0, x1, 6)
  x0 += ks2; x1 += k0 + 5u;
  o0 = x0; o1 = x1;
}

__device__ __forceinline__ float jax_erfinv(float x) {
  float w = -log1pf(-x * x);
  float p;
  if (w < 5.0f) {
    w -= 2.5f;
    p = 2.81022636e-08f;
    p = fmaf(p, w, 3.43273939e-07f);
    p = fmaf(p, w, -3.5233877e-06f);
    p = fmaf(p, w, -4.39150654e-06f);
    p = fmaf(p, w, 0.00021858087f);
    p = fmaf(p, w, -0.00125372503f);
    p = fmaf(p, w, -0.00417768164f);
    p = fmaf(p, w, 0.246640727f);
    p = fmaf(p, w, 1.50140941f);
  } else {
    w = sqrtf(w) - 3.0f;
    p = -0.000200214257f;
    p = fmaf(p, w, 0.000100950558f);
    p = fmaf(p, w, 0.00134934322f);
    p = fmaf(p, w, -0.00367342844f);
    p = fmaf(p, w, 0.00573950773f);
    p = fmaf(p, w, -0.0076224613f);
    p = fmaf(p, w, 0.00943887047f);
    p = fmaf(p, w, 1.00167406f);
    p = fmaf(p, w, 2.83297682f);
  }
  return p * x;
}

__device__ __forceinline__ float uni_from_bits(uint32_t bits) {
  float f = __uint_as_float((bits >> 9) | 0x3f800000u) - 1.0f;
  float x = f * 2.0f + (-0.99999994f);
  return fmaxf(-0.99999994f, x);
}

__device__ __forceinline__ float noise_from_bits(uint32_t bits) {
  float n = 1.41421356f * jax_erfinv(uni_from_bits(bits));
  return 0.15811388f * n;   // sqrt(2/A)*SIG = sqrt(10)*0.05
}

__device__ __forceinline__ float my_tanh(float x) {
  float e = __expf(2.0f * x);
  return 1.0f - 2.0f / (e + 1.0f);
}

__device__ __forceinline__ void pkfma(uint32_t& acc, uint32_t w, uint32_t h) {
  asm("v_pk_fma_f16 %0, %1, %2, %0" : "+v"(acc) : "v"(w), "v"(h));
}

__device__ __forceinline__ float cvt2f(uint32_t a) {
  f16x2 v = __builtin_bit_cast(f16x2, a);
  return (float)v.x + (float)v.y;
}

// opaque pin: forces the loaded value to stay in VGPRs (no rematerialized
// in-loop reloads — R8's VGPR_Count=64 proved W was never resident)
__device__ __forceinline__ u32x4 pin4(u32x4 x) { asm("" : "+v"(x)); return x; }
__device__ __forceinline__ float2 pin2(float2 x) { asm("" : "+v"(x)); return x; }

// LDS-only barrier (no vmcnt drain; stores/loads stay in flight)
__device__ __forceinline__ void step_barrier() {
  asm volatile("s_waitcnt lgkmcnt(0)" ::: "memory");
  __builtin_amdgcn_s_barrier();
}

// 4-lane allreduce: xor1 + xor2 via quad_perm DPP — pure VALU, no swizzle
__device__ __forceinline__ float allred4(float x) {
  int t = __builtin_amdgcn_update_dpp(0, __float_as_int(x), 0xB1, 0xF, 0xF, true);
  x += __int_as_float(t);
  t = __builtin_amdgcn_update_dpp(0, __float_as_int(x), 0x4E, 0xF, 0xF, true);
  x += __int_as_float(t);
  return x;
}

#define PKQ(acc, wq, hq) { pkfma(acc, (wq).x, (hq).x); pkfma(acc, (wq).y, (hq).y); \
                           pkfma(acc, (wq).z, (hq).z); pkfma(acc, (wq).w, (hq).w); }

// ---------------------------------------------------------------------------
__device__ __forceinline__ float wval(int j, int k,
    const float* w_ll, const float* w_rl, const float* w_lr, const float* w_rr) {
  if (j < 2) return (k < 2) ? w_ll[j * 2 + k] : w_rl[j * 256 + (k - 2)];
  return (k < 2) ? w_lr[(j - 2) * 2 + k] : w_rr[(j - 2) * 256 + (k - 2)];
}

__device__ __forceinline__ uint32_t packh2(float a, float b) {
  f16x2 h = __builtin_amdgcn_cvt_pkrtz(a, b);
  return __builtin_bit_cast(uint32_t, h);
}

// Wp: packed f16 pairs [258][128]; Wtail: f32 [258][2] (k=256,257).
__global__ __launch_bounds__(256) void build_w_kernel(
    const float* __restrict__ w_ll, const float* __restrict__ w_rl,
    const float* __restrict__ w_lr, const float* __restrict__ w_rr,
    uint32_t* __restrict__ Wp, float* __restrict__ Wtail) {
  int i = blockIdx.x * 256 + threadIdx.x;
  if (i < 258 * 128) {
    int j = i >> 7, kp = i & 127;
    float v0 = wval(j, 2 * kp, w_ll, w_rl, w_lr, w_rr);
    float v1 = wval(j, 2 * kp + 1, w_ll, w_rl, w_lr, w_rr);
    Wp[i] = packh2(v0, v1);
  }
  if (i < 516) {
    int j = i >> 1, k = 256 + (i & 1);
    Wtail[i] = wval(j, k, w_ll, w_rl, w_lr, w_rr);
  }
}

// ---------------------------------------------------------------------------
// K_scan: 512 blocks x 512 thr (1 batch row/block, 2 blocks/CU).
// Thread (g=tid>>2, ks=tid&3): rows j0=2+2g, j0+1; k in [64ks, 64ks+64).
// W pinned in 64 VGPRs. h packed f16 in LDS hbp[cur][0..127] + f32 tail
// [128],[129]. C generated on the fly (no gen_c kernel, no C in HBM).
// ---------------------------------------------------------------------------
__global__ __launch_bounds__(512, 4) void rnn_scan_kernel(
    const uint32_t* __restrict__ Wp, const float* __restrict__ Wtail,
    float* __restrict__ hsC,
    const float* __restrict__ w_ro, const float* __restrict__ b_ro,
    const float* __restrict__ xs,
    const float* __restrict__ w_xl, const float* __restrict__ w_xr,
    const float* __restrict__ b_ll, const float* __restrict__ b_rr,
    uint32_t k0a, uint32_t k0b, uint32_t k1a, uint32_t k1b,
    uint32_t k2a, uint32_t k2b) {
  __shared__ __align__(16) uint32_t hbp[2][132];
  __shared__ __align__(16) uint32_t wlp[2][132];
  __shared__ __align__(16) float cbuf[8][260];
  __shared__ __align__(16) float sbuf[8][260];
  __shared__ float wrol[260];
  __shared__ float uvb[400][4];     // u0,u1,v0,v1 per t
  __shared__ float wxr[256][2];
  __shared__ float brr[256];
  __shared__ float wxl[4];
  __shared__ float bll[2];

  const int tid = threadIdx.x;
  const int brow = blockIdx.x;
  const int ks = tid & 3;
  const int g  = tid >> 2;          // [0,128)
  const int j0 = 2 + 2 * g;
  const int lrow = (tid >= 4) ? 1 : 0;   // left-row duty for tid<8

  // --- pinned W registers: 2 rows x 8 quads (64 VGPR) + f32 tails ---
  u32x4 wr0[8], wr1[8];
  {
    const uint32_t* p0 = Wp + (size_t)j0 * 128 + 32 * ks;
    const uint32_t* p1 = p0 + 128;
#pragma unroll
    for (int c = 0; c < 8; ++c) {
      wr0[c] = pin4(*(const u32x4*)(p0 + 4 * c));
      wr1[c] = pin4(*(const u32x4*)(p1 + 4 * c));
    }
  }
  const float2 wt0 = pin2(*(const float2*)(Wtail + (size_t)j0 * 2));
  const float2 wt1 = pin2(*(const float2*)(Wtail + (size_t)j0 * 2 + 2));
  const float bro = b_ro[0];

  // --- staging ---
  if (tid < 256) {
    wxr[tid][0] = w_xr[2 * tid];
    wxr[tid][1] = w_xr[2 * tid + 1];
    brr[tid] = b_rr[tid];
    int row = tid >> 7, kp = tid & 127;
    wlp[row][kp] = Wp[row * 128 + kp];
  }
  if (tid < 4) wxl[tid] = w_xl[tid];
  if (tid < 2) bll[tid] = b_ll[tid];
  if (tid < 4) { int row = tid >> 1; wlp[row][128 + (tid & 1)] = __float_as_uint(Wtail[row * 2 + (tid & 1)]); }
  if (tid < 258) { int jj = (tid < 2) ? (256 + tid) : (tid - 2); wrol[jj] = w_ro[tid]; }
  for (int i2 = tid; i2 < 264; i2 += 512) ((uint32_t*)hbp)[i2] = 0u;

  // u,v for this row: uvb[t] = {u0,u1,v0,v1}
  for (int idx = tid; idx < 1600; idx += 512) {
    int t = idx >> 2, q = idx & 3;
    uint32_t e = (uint32_t)(brow * 800 + t * 2 + (q & 1));
    uint32_t o0, o1;
    if (q < 2) tf2x32(k0a, k0b, 0u, e, o0, o1);
    else       tf2x32(k1a, k1b, 0u, e, o0, o1);
    uvb[t][q] = xs[e] + noise_from_bits(o0 ^ o1);
  }
  __syncthreads();

  // C-chunk generator (replaces gen_c kernel)
  auto gen_cbuf = [&](int cc) {
#pragma unroll
    for (int q = 0; q < 5; ++q) {
      int idx = tid + 512 * q;
      if (idx < 2064) {
        int s = idx / 258;
        int j = idx - 258 * s;
        int t = cc * 8 + s;
        uint32_t o0, o1;
        tf2x32(k2a, k2b, 0u, (uint32_t)(t * 132096 + brow * 258 + j), o0, o1);
        float nz = noise_from_bits(o0 ^ o1);
        float inj;
        int jj;
        if (j < 2) {
          inj = wxl[2 * j] * uvb[t][0] + wxl[2 * j + 1] * uvb[t][1] + bll[j];
          jj = 256 + j;
        } else {
          int jr = j - 2;
          inj = wxr[jr][0] * uvb[t][2] + wxr[jr][1] * uvb[t][3] + brr[jr];
          jj = jr;
        }
        cbuf[s][jj] = inj + nz;
      }
    }
  };

  gen_cbuf(0);
  __syncthreads();

  float hcur = 0.f;   // row j0+ks (valid for ks<2)
  float hL = 0.f;     // left row lrow (valid for tid 0,4)

  float* gO = hsC + (size_t)brow * 103200;
  float* gZ = hsC + (size_t)52838400 + (size_t)brow * 400;

#pragma unroll 1
  for (int cc = 0; cc < 50; ++cc) {
#pragma unroll
    for (int s = 0; s < 8; ++s) {
      const int cur = s & 1, nxt = cur ^ 1;

      // early LDS prefetches (latency overlaps the dot)
      float t0 = __uint_as_float(hbp[cur][128]);
      float t1 = __uint_as_float(hbp[cur][129]);
      float2 cv = *(const float2*)&cbuf[s][2 * g];

      const uint32_t* hb = &hbp[cur][32 * ks];
      uint32_t acA0 = 0u, acA1 = 0u, acB0 = 0u, acB1 = 0u, lcA = 0u, lcB = 0u;
      {
        u32x4 h0 = *(const u32x4*)(hb + 0),  h1 = *(const u32x4*)(hb + 4),
              h2 = *(const u32x4*)(hb + 8),  h3 = *(const u32x4*)(hb + 12);
        PKQ(acA0, wr0[0], h0) PKQ(acA0, wr0[1], h1) PKQ(acA0, wr0[2], h2) PKQ(acA0, wr0[3], h3)
        PKQ(acA1, wr1[0], h0) PKQ(acA1, wr1[1], h1) PKQ(acA1, wr1[2], h2) PKQ(acA1, wr1[3], h3)
        if (tid < 8) {
          const uint32_t* wl = &wlp[lrow][32 * ks];
          u32x4 w0 = *(const u32x4*)(wl + 0), w1 = *(const u32x4*)(wl + 4),
                w2 = *(const u32x4*)(wl + 8), w3 = *(const u32x4*)(wl + 12);
          PKQ(lcA, w0, h0) PKQ(lcA, w1, h1) PKQ(lcA, w2, h2) PKQ(lcA, w3, h3)
        }
      }
      {
        u32x4 h0 = *(const u32x4*)(hb + 16), h1 = *(const u32x4*)(hb + 20),
              h2 = *(const u32x4*)(hb + 24), h3 = *(const u32x4*)(hb + 28);
        PKQ(acB0, wr0[4], h0) PKQ(acB0, wr0[5], h1) PKQ(acB0, wr0[6], h2) PKQ(acB0, wr0[7], h3)
        PKQ(acB1, wr1[4], h0) PKQ(acB1, wr1[5], h1) PKQ(acB1, wr1[6], h2) PKQ(acB1, wr1[7], h3)
        if (tid < 8) {
          const uint32_t* wl = &wlp[lrow][32 * ks + 16];
          u32x4 w0 = *(const u32x4*)(wl + 0), w1 = *(const u32x4*)(wl + 4),
                w2 = *(const u32x4*)(wl + 8), w3 = *(const u32x4*)(wl + 12);
          PKQ(lcB, w0, h0) PKQ(lcB, w1, h1) PKQ(lcB, w2, h2) PKQ(lcB, w3, h3)
        }
      }

      float a0 = allred4(cvt2f(acA0) + cvt2f(acB0));
      float a1 = allred4(cvt2f(acA1) + cvt2f(acB1));

      // main update: lane ks=r owns row j0+r (r=0,1)
      if (ks < 2) {
        float a   = ks ? a1 : a0;
        float2 wt = ks ? wt1 : wt0;
        float cvx = ks ? cv.y : cv.x;
        float pre = a + wt.x * t0 + wt.y * t1 + cvx;
        hcur = 0.8f * hcur + 0.2f * my_tanh(pre);
        sbuf[s][2 * g + ks] = hcur;
        if (g == 127) hbp[nxt][128 + ks] = __float_as_uint(hcur);
        else *(__fp16*)((char*)&hbp[nxt][0] + 4 * (1 + g) + 2 * ks) = (__fp16)hcur;
      }

      // left rows: lanes 0..7 (quad 0 -> row 0, quad 1 -> row 1)
      if (tid < 8) {
        float l = allred4(cvt2f(lcA) + cvt2f(lcB));
        if ((tid & 3) == 0) {
          float wlt0 = __uint_as_float(wlp[lrow][128]);
          float wlt1 = __uint_as_float(wlp[lrow][129]);
          float pre = l + wlt0 * t0 + wlt1 * t1 + cbuf[s][256 + lrow];
          hL = 0.8f * hL + 0.2f * my_tanh(pre);
          sbuf[s][256 + lrow] = hL;
          *(__fp16*)((char*)&hbp[nxt][0] + 2 * lrow) = (__fp16)hL;
        }
      }

      step_barrier();
    }

    // flush hs (coalesced)
    const int fb = cc * 2064;
#pragma unroll
    for (int q = 0; q < 5; ++q) {
      int idx = tid + 512 * q;
      if (idx < 2064) {
        int s = idx / 258, j = idx - 258 * s;
        int jj = (j < 2) ? (256 + j) : (j - 2);
        gO[fb + idx] = sbuf[s][jj];
      }
    }

    // zs: wave w handles step-slot s=w
    {
      int w = tid >> 6, lane = tid & 63;
      float zacc = 0.f;
#pragma unroll
      for (int q = 0; q < 5; ++q) {
        int jj = lane + 64 * q;
        if (jj < 258) zacc = fmaf(sbuf[w][jj], wrol[jj], zacc);
      }
#pragma unroll
      for (int m = 32; m >= 1; m >>= 1) zacc += __shfl_xor(zacc, m);
      if (lane == 0) gZ[cc * 8 + w] = zacc + bro;
    }

    // generate next C chunk (on the fly — was gen_c kernel + HBM round-trip)
    if (cc < 49) gen_cbuf(cc + 1);
    step_barrier();
  }
}

// ---------------------------------------------------------------------------
extern "C" void kernel_launch(void* const* d_in, const int* in_sizes, int n_in,
                              void* d_out, int out_size, void* d_ws, size_t ws_size,
                              hipStream_t stream) {
  const float* xs   = (const float*)d_in[0];
  const float* w_ll = (const float*)d_in[1];
  const float* b_ll = (const float*)d_in[2];
  const float* w_rr = (const float*)d_in[3];
  const float* b_rr = (const float*)d_in[4];
  const float* w_lr = (const float*)d_in[5];
  const float* w_rl = (const float*)d_in[6];
  const float* w_xl = (const float*)d_in[7];
  const float* w_xr = (const float*)d_in[8];
  const float* w_ro = (const float*)d_in[9];
  const float* b_ro = (const float*)d_in[10];

  float* hs = (float*)d_out;                    // 512*400*258 (+ zs after)

  uint32_t* Wp  = (uint32_t*)d_ws;              // 258*128 = 33,024 u32
  float* Wtail  = (float*)(Wp + 33024);         // 516

  uint32_t nk[3][2];
  for (uint32_t i = 0; i < 3; ++i) {
    uint32_t o0, o1;
    tf2x32(0u, 42u, 0u, i, o0, o1);
    nk[i][0] = o0; nk[i][1] = o1;
  }

  build_w_kernel<<<129, 256, 0, stream>>>(w_ll, w_rl, w_lr, w_rr, Wp, Wtail);
  rnn_scan_kernel<<<512, 512, 0, stream>>>(Wp, Wtail, hs, w_ro, b_ro, xs,
                                           w_xl, w_xr, b_ll, b_rr,
                                           nk[0][0], nk[0][1], nk[1][0], nk[1][1],
                                           nk[2][0], nk[2][1]);
}